// Round 1
// baseline (523.425 us; speedup 1.0000x reference)
//
#include <hip/hip_runtime.h>

#define HH 512
#define WWID 512
#define CIN 64
#define COUT 64
#define TH 8
#define TW 32

// 1/sqrt(#valid positions in {y-1,y,y+1} within [0,n))
__device__ __forceinline__ float edge_rsqrt(int y, int n) {
  int r = 1 + (y > 0 ? 1 : 0) + (y < n - 1 ? 1 : 0);
  return __frsqrt_rn((float)r);
}

__global__ __launch_bounds__(256, 4)
void gcn_fused(const float* __restrict__ x, const float* __restrict__ wgt,
               float* __restrict__ out) {
  // per-phase t-tiles: one 256-float tile per wave (channel 4*ci+og)
  __shared__ __align__(16) float ts[4][TH * TW];

  const int t  = threadIdx.x;
  const int g  = t & 63;                                   // pixel group 0..63
  const int og = __builtin_amdgcn_readfirstlane(t >> 6);   // wave id 0..3 (uniform)
  const int b  = blockIdx.z;
  const int h0 = blockIdx.y * TH;
  const int w0 = blockIdx.x * TW;
  const int row = g >> 3;          // 0..7
  const int cg  = g & 7;           // 0..7 column group (4 pixels each)
  const int h = h0 + row;
  const int w = w0 + cg * 4;

  // row factors (dinv row component) for rows h-1..h+1; 0 if out of image
  float srh[3]; int hi[3];
#pragma unroll
  for (int i = 0; i < 3; ++i) {
    int y = h - 1 + i;
    bool v = (y >= 0) && (y < HH);
    srh[i] = v ? edge_rsqrt(y, HH) : 0.0f;
    hi[i] = v ? y : h;  // clamped (factor 0 kills the value)
  }
  // column factors for cols w-1..w+4
  float srw[6];
#pragma unroll
  for (int j = 0; j < 6; ++j) {
    int xw = w - 1 + j;
    bool v = (xw >= 0) && (xw < WWID);
    srw[j] = v ? edge_rsqrt(xw, WWID) : 0.0f;
  }
  const int wl = (w > 0) ? (w - 1) : w;                // clamped left col
  const int wr = (w + 4 < WWID) ? (w + 4) : w;         // clamped right col
  // outer dinv for this thread's 4 output pixels
  const float dp0 = srh[1] * srw[1];
  const float dp1 = srh[1] * srw[2];
  const float dp2 = srh[1] * srw[3];
  const float dp3 = srh[1] * srw[4];

  float4 acc[16];
#pragma unroll
  for (int j = 0; j < 16; ++j) acc[j] = make_float4(0.f, 0.f, 0.f, 0.f);

  const size_t plane = (size_t)HH * WWID;
  const float* xb = x + (size_t)b * CIN * plane;

  // prologue: load rows for channel c = og (phase 0)
  float lv[3], rv[3]; float4 mv[3];
  {
    const float* xp = xb + (size_t)og * plane;
#pragma unroll
    for (int i = 0; i < 3; ++i) {
      const float* rp = xp + (size_t)hi[i] * WWID;
      lv[i] = rp[wl];
      mv[i] = *(const float4*)(rp + w);
      rv[i] = rp[wr];
    }
  }

  for (int ci = 0; ci < 16; ++ci) {
    // stencil: t_k = sum_i srh[i] * sum_{j=k..k+2} srw[j]*v[j]
    float t0 = 0.f, t1 = 0.f, t2 = 0.f, t3 = 0.f;
#pragma unroll
    for (int i = 0; i < 3; ++i) {
      float m0 = lv[i] * srw[0];
      float m1 = mv[i].x * srw[1];
      float m2 = mv[i].y * srw[2];
      float m3 = mv[i].z * srw[3];
      float m4 = mv[i].w * srw[4];
      float m5 = rv[i] * srw[5];
      t0 += srh[i] * (m0 + m1 + m2);
      t1 += srh[i] * (m1 + m2 + m3);
      t2 += srh[i] * (m2 + m3 + m4);
      t3 += srh[i] * (m3 + m4 + m5);
    }
    __syncthreads();  // previous phase's GEMM finished reading ts
    *(float4*)&ts[og][4 * g] = make_float4(t0, t1, t2, t3);
    __syncthreads();  // ts ready

    // prefetch next phase's x rows; latency hidden under the GEMM below
    if (ci < 15) {
      const float* xp = xb + (size_t)((ci + 1) * 4 + og) * plane;
#pragma unroll
      for (int i = 0; i < 3; ++i) {
        const float* rp = xp + (size_t)hi[i] * WWID;
        lv[i] = rp[wl];
        mv[i] = *(const float4*)(rp + w);
        rv[i] = rp[wr];
      }
    }

    // GEMM: 4 channels x 16 output cols; W via uniform (scalar) loads
#pragma unroll
    for (int cc = 0; cc < 4; ++cc) {
      float4 tv = *(const float4*)&ts[cc][4 * g];
      const float* wp = wgt + (ci * 4 + cc) * COUT + og * 16;
#pragma unroll
      for (int j = 0; j < 16; ++j) {
        float wj = wp[j];
        acc[j].x += tv.x * wj;
        acc[j].y += tv.y * wj;
        acc[j].z += tv.z * wj;
        acc[j].w += tv.w * wj;
      }
    }
  }

  // epilogue: apply outer dinv, store [b][o][h][w]
  float* ob = out + (size_t)b * COUT * plane + (size_t)h * WWID + w;
#pragma unroll
  for (int j = 0; j < 16; ++j) {
    int o = og * 16 + j;
    float4 r;
    r.x = acc[j].x * dp0;
    r.y = acc[j].y * dp1;
    r.z = acc[j].z * dp2;
    r.w = acc[j].w * dp3;
    *(float4*)(ob + (size_t)o * plane) = r;
  }
}

extern "C" void kernel_launch(void* const* d_in, const int* in_sizes, int n_in,
                              void* d_out, int out_size, void* d_ws, size_t ws_size,
                              hipStream_t stream) {
  const float* x = (const float*)d_in[0];
  const float* wgt = (const float*)d_in[1];
  float* out = (float*)d_out;
  dim3 grid(WWID / TW, HH / TH, 4);  // 16 x 64 x 4 = 4096 blocks
  gcn_fused<<<grid, dim3(256), 0, stream>>>(x, wgt, out);
}